// Round 3
// baseline (439.607 us; speedup 1.0000x reference)
//
#include <hip/hip_runtime.h>

typedef unsigned int   u32;
typedef unsigned short u16;
typedef __attribute__((ext_vector_type(8)))  short  short8;
typedef __attribute__((ext_vector_type(16))) float  f32x16;
typedef __attribute__((ext_vector_type(4)))  float  f32x4;
typedef __attribute__((ext_vector_type(2)))  float  f32x2;
typedef __attribute__((ext_vector_type(4)))  u32    u32x4;
typedef __attribute__((ext_vector_type(2)))  u32    u32x2;

#define DEV static __device__ __forceinline__

// bf16 hi/lo split, truncation-based (residual <= 2^-16 relative)
DEV u32   bfhi(float f)   { return __float_as_uint(f) >> 16; }
DEV float bfhi_f(float f) { return __uint_as_float(__float_as_uint(f) & 0xFFFF0000u); }
DEV u32   bflo(float f)   { return __float_as_uint(f - bfhi_f(f)) >> 16; }

DEV f32x16 zero16() {
  f32x16 z;
  #pragma unroll
  for (int i = 0; i < 16; ++i) z[i] = 0.f;
  return z;
}

#define NBATCH 16384
#define NHID   1024
#define NCODE  512
#define TB     64
// ws layout in u16: W0 frags [0, 1048576), then 6x 524288 for Ws[t]
#define W0_U16 1048576
#define WT_U16 524288

// ---------------- prep: weights -> pre-swizzled bf16 hi/lo fragments ----------------
// Fragment block (m, ks, p): 1 KiB, lane l holds W[m*32 + (l&31)][ks*16 + (l>>5)*8 + j], j=0..7
__global__ __launch_bounds__(256)
void hh_prep(const float* __restrict__ W0, const float* __restrict__ Ws, u16* __restrict__ wf)
{
  const int tid  = blockIdx.x * 256 + threadIdx.x;
  const int task = tid >> 6;
  const int l    = tid & 63;
  const int lrow = l & 31;
  const int h    = l >> 5;
  const float* src;
  u16* dst;
  if (task < 1024) {                       // W0: m 0..15, ks 0..63
    const int m = task >> 6, ks = task & 63;
    src = W0 + (size_t)(m * 32 + lrow) * NHID + ks * 16 + h * 8;
    dst = wf + (size_t)task * 1024 + l * 8;
  } else {                                 // Ws: t 0..5, m 0..15, ks 0..31
    const int t2 = task - 1024;
    const int t = t2 >> 9, rr = t2 & 511;
    const int m = rr >> 5, ks = rr & 31;
    src = Ws + (size_t)t * (NCODE * NCODE) + (size_t)(m * 32 + lrow) * NCODE + ks * 16 + h * 8;
    dst = wf + W0_U16 + (size_t)t * WT_U16 + (size_t)rr * 1024 + l * 8;
  }
  f32x4 f0 = *(const f32x4*)(src);
  f32x4 f1 = *(const f32x4*)(src + 4);
  short8 hi, lo;
  #pragma unroll
  for (int j = 0; j < 4; ++j) {
    hi[j]     = (short)bfhi(f0[j]);  lo[j]     = (short)bflo(f0[j]);
    hi[j + 4] = (short)bfhi(f1[j]);  lo[j + 4] = (short)bflo(f1[j]);
  }
  *(short8*)(dst)       = hi;   // p=0 (hi)
  *(short8*)(dst + 512) = lo;   // p=1 (lo)
}

// ---------------- fused flow kernel ----------------
#define LDA(buf, kk) do { \
  const u16* _p = aPtr + (size_t)(kk) * 1024; \
  buf[0][0] = *(const short8*)(_p); \
  buf[0][1] = *(const short8*)(_p + 512); \
  buf[1][0] = *(const short8*)(_p + mStrideU16); \
  buf[1][1] = *(const short8*)(_p + mStrideU16 + 512); \
} while (0)

#define LDB(buf, kk) do { \
  const u32 _x = (u32)(kk) * 32u; \
  buf[0][0] = *(const short8*)(vthi + (bOff0 ^ _x)); \
  buf[0][1] = *(const short8*)(vtlo + (bOff0 ^ _x)); \
  buf[1][0] = *(const short8*)(vthi + (bOff1 ^ _x)); \
  buf[1][1] = *(const short8*)(vtlo + (bOff1 ^ _x)); \
} while (0)

#define MFMA_(a, b, c) __builtin_amdgcn_mfma_f32_32x32x16_bf16(a, b, c, 0, 0, 0)
// 3-pass hi/lo: hiA*hiB, loA*hiB, hiA*loB over the 2x2 tile grid
#define DO_MMA(A_, B_) do { \
  acc[0][0] = MFMA_(A_[0][0], B_[0][0], acc[0][0]); \
  acc[0][1] = MFMA_(A_[0][0], B_[1][0], acc[0][1]); \
  acc[1][0] = MFMA_(A_[1][0], B_[0][0], acc[1][0]); \
  acc[1][1] = MFMA_(A_[1][0], B_[1][0], acc[1][1]); \
  acc[0][0] = MFMA_(A_[0][1], B_[0][0], acc[0][0]); \
  acc[0][1] = MFMA_(A_[0][1], B_[1][0], acc[0][1]); \
  acc[1][0] = MFMA_(A_[1][1], B_[0][0], acc[1][0]); \
  acc[1][1] = MFMA_(A_[1][1], B_[1][0], acc[1][1]); \
  acc[0][0] = MFMA_(A_[0][0], B_[0][1], acc[0][0]); \
  acc[0][1] = MFMA_(A_[0][0], B_[1][1], acc[0][1]); \
  acc[1][0] = MFMA_(A_[1][0], B_[0][1], acc[1][0]); \
  acc[1][1] = MFMA_(A_[1][0], B_[1][1], acc[1][1]); \
} while (0)

__global__ __launch_bounds__(512, 2)
void hh_main(const float* __restrict__ hidden, const float* __restrict__ zs,
             const float* __restrict__ b0v, const float* __restrict__ bsv,
             const u16* __restrict__ wf, float* __restrict__ out)
{
  extern __shared__ char smem[];
  char*  vthi = smem;                       // 64 KiB: v^T hi, [64 batch][512 k] bf16, XOR-swizzled
  char*  vtlo = smem + 65536;               // 64 KiB: v^T lo
  float* pbuf = (float*)(smem + 131072);    // [8 waves][64 batch][2] partial {vz, vv}

  const int tid  = threadIdx.x;
  const int w    = tid >> 6;     // wave id: owns out-rows [w*64, w*64+64)
  const int l    = tid & 63;
  const int lrow = l & 31;
  const int h    = l >> 5;
  const int brow = blockIdx.x * TB;

  f32x16 acc[2][2];   // [mi out-tile][ni batch-tile]; C layout: col=lane&31=batch, row=(r&3)+8*(r>>2)+4*h
  f32x16 zf[2][2];    // z held in identical layout

  // ---- z init from zs ----
  #pragma unroll
  for (int mi = 0; mi < 2; ++mi)
    #pragma unroll
    for (int ni = 0; ni < 2; ++ni)
      #pragma unroll
      for (int q = 0; q < 4; ++q) {
        const int batch = brow + ni * 32 + lrow;
        const int n     = w * 64 + mi * 32 + q * 8 + h * 4;
        f32x4 v = *(const f32x4*)(zs + (size_t)batch * NCODE + n);
        #pragma unroll
        for (int c = 0; c < 4; ++c) zf[mi][ni][q * 4 + c] = v[c];
      }
  #pragma unroll
  for (int mi = 0; mi < 2; ++mi) { acc[mi][0] = zero16(); acc[mi][1] = zero16(); }

  // ---- stage hidden chunk (512 k) into VT hi/lo, cooperatively ----
  auto stage_hidden = [&](int c2) {
    const int bloc = tid >> 3;          // 0..63 batch row
    const int kc   = tid & 7;           // 0..7  k-chunk of 64
    const float* src = hidden + (size_t)(brow + bloc) * NHID + c2 * 512 + kc * 64;
    const u32 rowb = (u32)bloc * 1024u;
    const u32 swz  = ((u32)bloc & 31u) << 4;
    #pragma unroll
    for (int i = 0; i < 8; ++i) {
      f32x4 f0 = *(const f32x4*)(src + i * 8);
      f32x4 f1 = *(const f32x4*)(src + i * 8 + 4);
      u32x4 sh, sl;
      sh[0] = bfhi(f0[0]) | (bfhi(f0[1]) << 16);
      sh[1] = bfhi(f0[2]) | (bfhi(f0[3]) << 16);
      sh[2] = bfhi(f1[0]) | (bfhi(f1[1]) << 16);
      sh[3] = bfhi(f1[2]) | (bfhi(f1[3]) << 16);
      sl[0] = bflo(f0[0]) | (bflo(f0[1]) << 16);
      sl[1] = bflo(f0[2]) | (bflo(f0[3]) << 16);
      sl[2] = bflo(f1[0]) | (bflo(f1[1]) << 16);
      sl[3] = bflo(f1[2]) | (bflo(f1[3]) << 16);
      const u32 kloc = (u32)(kc * 64 + i * 8);
      const u32 off  = rowb + ((kloc * 2u) ^ swz);
      *(u32x4*)(vthi + off) = sh;
      *(u32x4*)(vtlo + off) = sl;
    }
  };

  // ---- one 512-K GEMM pass: acc += W_frag * VT ----
  auto gemm = [&](const u16* aBase, int mStrideU16, int ksOff) {
    const u16* aPtr = aBase + (size_t)(w * 2) * mStrideU16 + (size_t)ksOff * 1024 + (size_t)l * 8;
    const u32 bOff0 = (u32)lrow * 1024u + (((u32)h * 16u) ^ ((u32)lrow << 4));
    const u32 bOff1 = bOff0 + 32768u;   // ni=1 -> +32 rows
    short8 A0[2][2], A1[2][2], B0[2][2], B1[2][2];
    LDA(A0, 0); LDB(B0, 0);
    for (int kp = 0; kp < 15; ++kp) {
      LDA(A1, 2 * kp + 1); LDB(B1, 2 * kp + 1);
      DO_MMA(A0, B0);
      LDA(A0, 2 * kp + 2); LDB(B0, 2 * kp + 2);
      DO_MMA(A1, B1);
    }
    LDA(A1, 31); LDB(B1, 31);
    DO_MMA(A0, B0);
    DO_MMA(A1, B1);
  };

  // ---- epilogue: bias, HH partials, write v^T hi/lo, barrier, z update, clear acc ----
  auto epilogue = [&](const float* bias, bool writeVT) {
    #pragma unroll
    for (int mi = 0; mi < 2; ++mi)
      #pragma unroll
      for (int q = 0; q < 4; ++q) {
        f32x4 bb = *(const f32x4*)(bias + w * 64 + mi * 32 + q * 8 + h * 4);
        #pragma unroll
        for (int c = 0; c < 4; ++c) {
          acc[mi][0][q * 4 + c] += bb[c];
          acc[mi][1][q * 4 + c] += bb[c];
        }
      }
    float pvz0 = 0.f, pvv0 = 0.f, pvz1 = 0.f, pvv1 = 0.f;
    #pragma unroll
    for (int mi = 0; mi < 2; ++mi)
      #pragma unroll
      for (int r = 0; r < 16; ++r) {
        pvz0 += acc[mi][0][r] * zf[mi][0][r];
        pvv0 += acc[mi][0][r] * acc[mi][0][r];
        pvz1 += acc[mi][1][r] * zf[mi][1][r];
        pvv1 += acc[mi][1][r] * acc[mi][1][r];
      }
    pvz0 += __shfl_xor(pvz0, 32); pvv0 += __shfl_xor(pvv0, 32);
    pvz1 += __shfl_xor(pvz1, 32); pvv1 += __shfl_xor(pvv1, 32);

    if (writeVT) {
      #pragma unroll
      for (int mi = 0; mi < 2; ++mi)
        #pragma unroll
        for (int ni = 0; ni < 2; ++ni) {
          const u32 rowb = (u32)(ni * 32 + lrow) * 1024u;
          const u32 swz  = (u32)lrow << 4;
          #pragma unroll
          for (int q = 0; q < 4; ++q) {
            const float x0 = acc[mi][ni][q * 4 + 0], x1 = acc[mi][ni][q * 4 + 1];
            const float x2 = acc[mi][ni][q * 4 + 2], x3 = acc[mi][ni][q * 4 + 3];
            u32x2 ph, pl;
            ph[0] = bfhi(x0) | (bfhi(x1) << 16);
            ph[1] = bfhi(x2) | (bfhi(x3) << 16);
            pl[0] = bflo(x0) | (bflo(x1) << 16);
            pl[1] = bflo(x2) | (bflo(x3) << 16);
            const u32 kg  = (u32)(w * 64 + mi * 32 + q * 8 + h * 4);
            const u32 off = rowb + ((kg * 2u) ^ swz);
            *(u32x2*)(vthi + off) = ph;
            *(u32x2*)(vtlo + off) = pl;
          }
        }
    }
    if (h == 0) {
      f32x2 p0, p1;
      p0[0] = pvz0; p0[1] = pvv0;
      p1[0] = pvz1; p1[1] = pvv1;
      *(f32x2*)(pbuf + (size_t)(w * 64 + lrow) * 2)      = p0;
      *(f32x2*)(pbuf + (size_t)(w * 64 + 32 + lrow) * 2) = p1;
    }
    __syncthreads();
    float svz0 = 0.f, svv0 = 0.f, svz1 = 0.f, svv1 = 0.f;
    #pragma unroll
    for (int w2 = 0; w2 < 8; ++w2) {
      f32x2 p0 = *(const f32x2*)(pbuf + (size_t)(w2 * 64 + lrow) * 2);
      f32x2 p1 = *(const f32x2*)(pbuf + (size_t)(w2 * 64 + 32 + lrow) * 2);
      svz0 += p0[0]; svv0 += p0[1];
      svz1 += p1[0]; svv1 += p1[1];
    }
    const float c0 = 2.0f * svz0 / svv0;
    const float c1 = 2.0f * svz1 / svv1;
    #pragma unroll
    for (int mi = 0; mi < 2; ++mi)
      #pragma unroll
      for (int r = 0; r < 16; ++r) {
        zf[mi][0][r] = fmaf(-c0, acc[mi][0][r], zf[mi][0][r]);
        zf[mi][1][r] = fmaf(-c1, acc[mi][1][r], zf[mi][1][r]);
      }
    #pragma unroll
    for (int mi = 0; mi < 2; ++mi) { acc[mi][0] = zero16(); acc[mi][1] = zero16(); }
  };

  // ---- layer 0: K=1024 via two staged chunks of hidden ----
  for (int c2 = 0; c2 < 2; ++c2) {
    stage_hidden(c2);
    __syncthreads();
    gemm(wf, 65536, c2 * 32);          // W0 frags: m-stride 64 ksteps * 1024 u16
    __syncthreads();
  }
  epilogue(b0v, true);

  // ---- layers 1..6 ----
  for (int t = 0; t < 6; ++t) {
    gemm(wf + W0_U16 + (size_t)t * WT_U16, 32768, 0);
    __syncthreads();
    epilogue(bsv + t * NCODE, t < 5);
  }

  // ---- store z ----
  #pragma unroll
  for (int mi = 0; mi < 2; ++mi)
    #pragma unroll
    for (int ni = 0; ni < 2; ++ni)
      #pragma unroll
      for (int q = 0; q < 4; ++q) {
        const int batch = brow + ni * 32 + lrow;
        const int n     = w * 64 + mi * 32 + q * 8 + h * 4;
        f32x4 v;
        #pragma unroll
        for (int c = 0; c < 4; ++c) v[c] = zf[mi][ni][q * 4 + c];
        *(f32x4*)(out + (size_t)batch * NCODE + n) = v;
      }
}

extern "C" void kernel_launch(void* const* d_in, const int* in_sizes, int n_in,
                              void* d_out, int out_size, void* d_ws, size_t ws_size,
                              hipStream_t stream)
{
  const float* hidden = (const float*)d_in[0];
  const float* zs     = (const float*)d_in[1];
  const float* W0     = (const float*)d_in[2];
  const float* b0v    = (const float*)d_in[3];
  const float* Ws     = (const float*)d_in[4];
  const float* bsv    = (const float*)d_in[5];
  float* out = (float*)d_out;
  u16*   wf  = (u16*)d_ws;   // needs 8 MiB

  hh_prep<<<1024, 256, 0, stream>>>(W0, Ws, wf);

  (void)hipFuncSetAttribute((const void*)hh_main, hipFuncAttributeMaxDynamicSharedMemorySize, 135168);
  hh_main<<<256, 512, 135168, stream>>>(hidden, zs, b0v, bsv, wf, out);
}

// Round 4
// 426.366 us; speedup vs baseline: 1.0311x; 1.0311x over previous
//
#include <hip/hip_runtime.h>

typedef unsigned int   u32;
typedef unsigned short u16;
typedef __attribute__((ext_vector_type(8)))  short  short8;
typedef __attribute__((ext_vector_type(16))) float  f32x16;
typedef __attribute__((ext_vector_type(4)))  float  f32x4;
typedef __attribute__((ext_vector_type(2)))  float  f32x2;
typedef __attribute__((ext_vector_type(4)))  u32    u32x4;
typedef __attribute__((ext_vector_type(2)))  u32    u32x2;

#define DEV static __device__ __forceinline__

// bf16 hi/lo split, truncation-based (residual <= 2^-16 relative)
DEV u32   bfhi(float f)   { return __float_as_uint(f) >> 16; }
DEV float bfhi_f(float f) { return __uint_as_float(__float_as_uint(f) & 0xFFFF0000u); }
DEV u32   bflo(float f)   { return __float_as_uint(f - bfhi_f(f)) >> 16; }

DEV f32x16 zero16() {
  f32x16 z;
  #pragma unroll
  for (int i = 0; i < 16; ++i) z[i] = 0.f;
  return z;
}

#define NBATCH 16384
#define NHID   1024
#define NCODE  512
#define TB     64
// ws layout in u16: W0 frags [0, 1048576), then 6x 524288 for Ws[t]
#define W0_U16 1048576
#define WT_U16 524288

// ---------------- prep: weights -> pre-swizzled bf16 hi/lo fragments ----------------
// Fragment block (m, ks, p): 1 KiB, lane l holds W[m*32 + (l&31)][ks*16 + (l>>5)*8 + j], j=0..7
__global__ __launch_bounds__(256)
void hh_prep(const float* __restrict__ W0, const float* __restrict__ Ws, u16* __restrict__ wf)
{
  const int tid  = blockIdx.x * 256 + threadIdx.x;
  const int task = tid >> 6;
  const int l    = tid & 63;
  const int lrow = l & 31;
  const int h    = l >> 5;
  const float* src;
  u16* dst;
  if (task < 1024) {                       // W0: m 0..15, ks 0..63
    const int m = task >> 6, ks = task & 63;
    src = W0 + (size_t)(m * 32 + lrow) * NHID + ks * 16 + h * 8;
    dst = wf + (size_t)task * 1024 + l * 8;
  } else {                                 // Ws: t 0..5, m 0..15, ks 0..31
    const int t2 = task - 1024;
    const int t = t2 >> 9, rr = t2 & 511;
    const int m = rr >> 5, ks = rr & 31;
    src = Ws + (size_t)t * (NCODE * NCODE) + (size_t)(m * 32 + lrow) * NCODE + ks * 16 + h * 8;
    dst = wf + W0_U16 + (size_t)t * WT_U16 + (size_t)rr * 1024 + l * 8;
  }
  f32x4 f0 = *(const f32x4*)(src);
  f32x4 f1 = *(const f32x4*)(src + 4);
  short8 hi, lo;
  #pragma unroll
  for (int j = 0; j < 4; ++j) {
    hi[j]     = (short)bfhi(f0[j]);  lo[j]     = (short)bflo(f0[j]);
    hi[j + 4] = (short)bfhi(f1[j]);  lo[j + 4] = (short)bflo(f1[j]);
  }
  *(short8*)(dst)       = hi;   // p=0 (hi)
  *(short8*)(dst + 512) = lo;   // p=1 (lo)
}

// ---------------- fused flow kernel ----------------
#define LDA(buf, kk) do { \
  const u16* _p = aPtr + (size_t)(kk) * 1024; \
  buf[0][0] = *(const short8*)(_p); \
  buf[0][1] = *(const short8*)(_p + 512); \
  buf[1][0] = *(const short8*)(_p + mStrideU16); \
  buf[1][1] = *(const short8*)(_p + mStrideU16 + 512); \
} while (0)

#define LDB(buf, kk) do { \
  const u32 _x = (u32)(kk) * 32u; \
  buf[0][0] = *(const short8*)(vthi + (bOff0 ^ _x)); \
  buf[0][1] = *(const short8*)(vtlo + (bOff0 ^ _x)); \
  buf[1][0] = *(const short8*)(vthi + (bOff1 ^ _x)); \
  buf[1][1] = *(const short8*)(vtlo + (bOff1 ^ _x)); \
} while (0)

#define MFMA_(a, b, c) __builtin_amdgcn_mfma_f32_32x32x16_bf16(a, b, c, 0, 0, 0)
// 3-pass hi/lo: hiA*hiB, loA*hiB, hiA*loB over the 2x2 tile grid
#define DO_MMA(A_, B_) do { \
  acc[0][0] = MFMA_(A_[0][0], B_[0][0], acc[0][0]); \
  acc[0][1] = MFMA_(A_[0][0], B_[1][0], acc[0][1]); \
  acc[1][0] = MFMA_(A_[1][0], B_[0][0], acc[1][0]); \
  acc[1][1] = MFMA_(A_[1][0], B_[1][0], acc[1][1]); \
  acc[0][0] = MFMA_(A_[0][1], B_[0][0], acc[0][0]); \
  acc[0][1] = MFMA_(A_[0][1], B_[1][0], acc[0][1]); \
  acc[1][0] = MFMA_(A_[1][1], B_[0][0], acc[1][0]); \
  acc[1][1] = MFMA_(A_[1][1], B_[1][0], acc[1][1]); \
  acc[0][0] = MFMA_(A_[0][0], B_[0][1], acc[0][0]); \
  acc[0][1] = MFMA_(A_[0][0], B_[1][1], acc[0][1]); \
  acc[1][0] = MFMA_(A_[1][0], B_[0][1], acc[1][0]); \
  acc[1][1] = MFMA_(A_[1][0], B_[1][1], acc[1][1]); \
} while (0)

__global__ __launch_bounds__(512, 1)
void hh_main(const float* __restrict__ hidden, const float* __restrict__ zs,
             const float* __restrict__ b0v, const float* __restrict__ bsv,
             const u16* __restrict__ wf, float* __restrict__ out)
{
  extern __shared__ char smem[];
  char*  vthi = smem;                       // 64 KiB: v^T hi, [64 batch][512 k] bf16, XOR-swizzled
  char*  vtlo = smem + 65536;               // 64 KiB: v^T lo
  float* pbuf = (float*)(smem + 131072);    // [8 waves][64 batch][2] partial {vz, vv}

  const int tid  = threadIdx.x;
  const int w    = tid >> 6;     // wave id: owns out-rows [w*64, w*64+64)
  const int l    = tid & 63;
  const int lrow = l & 31;
  const int h    = l >> 5;
  const int brow = blockIdx.x * TB;

  f32x16 acc[2][2];   // [mi out-tile][ni batch-tile]; C layout: col=lane&31=batch, row=(r&3)+8*(r>>2)+4*h
  f32x16 zf[2][2];    // z held in identical layout

  // ---- z init from zs ----
  #pragma unroll
  for (int mi = 0; mi < 2; ++mi)
    #pragma unroll
    for (int ni = 0; ni < 2; ++ni)
      #pragma unroll
      for (int q = 0; q < 4; ++q) {
        const int batch = brow + ni * 32 + lrow;
        const int n     = w * 64 + mi * 32 + q * 8 + h * 4;
        f32x4 v = *(const f32x4*)(zs + (size_t)batch * NCODE + n);
        #pragma unroll
        for (int c = 0; c < 4; ++c) zf[mi][ni][q * 4 + c] = v[c];
      }
  #pragma unroll
  for (int mi = 0; mi < 2; ++mi) { acc[mi][0] = zero16(); acc[mi][1] = zero16(); }

  // ---- stage hidden chunk (512 k) into VT hi/lo, cooperatively ----
  auto stage_hidden = [&](int c2) {
    const int bloc = tid >> 3;          // 0..63 batch row
    const int kc   = tid & 7;           // 0..7  k-chunk of 64
    const float* src = hidden + (size_t)(brow + bloc) * NHID + c2 * 512 + kc * 64;
    const u32 rowb = (u32)bloc * 1024u;
    const u32 swz  = ((u32)bloc & 31u) << 4;
    #pragma unroll
    for (int i = 0; i < 8; ++i) {
      f32x4 f0 = *(const f32x4*)(src + i * 8);
      f32x4 f1 = *(const f32x4*)(src + i * 8 + 4);
      u32x4 sh, sl;
      sh[0] = bfhi(f0[0]) | (bfhi(f0[1]) << 16);
      sh[1] = bfhi(f0[2]) | (bfhi(f0[3]) << 16);
      sh[2] = bfhi(f1[0]) | (bfhi(f1[1]) << 16);
      sh[3] = bfhi(f1[2]) | (bfhi(f1[3]) << 16);
      sl[0] = bflo(f0[0]) | (bflo(f0[1]) << 16);
      sl[1] = bflo(f0[2]) | (bflo(f0[3]) << 16);
      sl[2] = bflo(f1[0]) | (bflo(f1[1]) << 16);
      sl[3] = bflo(f1[2]) | (bflo(f1[3]) << 16);
      const u32 kloc = (u32)(kc * 64 + i * 8);
      const u32 off  = rowb + ((kloc * 2u) ^ swz);
      *(u32x4*)(vthi + off) = sh;
      *(u32x4*)(vtlo + off) = sl;
    }
  };

  // ---- one 512-K GEMM pass: acc += W_frag * VT ----
  auto gemm = [&](const u16* aBase, int mStrideU16, int ksOff) {
    const u16* aPtr = aBase + (size_t)(w * 2) * mStrideU16 + (size_t)ksOff * 1024 + (size_t)l * 8;
    const u32 bOff0 = (u32)lrow * 1024u + (((u32)h * 16u) ^ ((u32)lrow << 4));
    const u32 bOff1 = bOff0 + 32768u;   // ni=1 -> +32 rows
    short8 A0[2][2], A1[2][2], B0[2][2], B1[2][2];
    LDA(A0, 0); LDB(B0, 0);
    for (int kp = 0; kp < 15; ++kp) {
      LDA(A1, 2 * kp + 1); LDB(B1, 2 * kp + 1);
      DO_MMA(A0, B0);
      LDA(A0, 2 * kp + 2); LDB(B0, 2 * kp + 2);
      DO_MMA(A1, B1);
    }
    LDA(A1, 31); LDB(B1, 31);
    DO_MMA(A0, B0);
    DO_MMA(A1, B1);
  };

  // ---- epilogue: bias, HH partials, write v^T hi/lo, barrier, z update, clear acc ----
  auto epilogue = [&](const float* bias, bool writeVT) {
    #pragma unroll
    for (int mi = 0; mi < 2; ++mi)
      #pragma unroll
      for (int q = 0; q < 4; ++q) {
        f32x4 bb = *(const f32x4*)(bias + w * 64 + mi * 32 + q * 8 + h * 4);
        #pragma unroll
        for (int c = 0; c < 4; ++c) {
          acc[mi][0][q * 4 + c] += bb[c];
          acc[mi][1][q * 4 + c] += bb[c];
        }
      }
    float pvz0 = 0.f, pvv0 = 0.f, pvz1 = 0.f, pvv1 = 0.f;
    #pragma unroll
    for (int mi = 0; mi < 2; ++mi)
      #pragma unroll
      for (int r = 0; r < 16; ++r) {
        pvz0 += acc[mi][0][r] * zf[mi][0][r];
        pvv0 += acc[mi][0][r] * acc[mi][0][r];
        pvz1 += acc[mi][1][r] * zf[mi][1][r];
        pvv1 += acc[mi][1][r] * acc[mi][1][r];
      }
    pvz0 += __shfl_xor(pvz0, 32); pvv0 += __shfl_xor(pvv0, 32);
    pvz1 += __shfl_xor(pvz1, 32); pvv1 += __shfl_xor(pvv1, 32);

    if (writeVT) {
      #pragma unroll
      for (int mi = 0; mi < 2; ++mi)
        #pragma unroll
        for (int ni = 0; ni < 2; ++ni) {
          const u32 rowb = (u32)(ni * 32 + lrow) * 1024u;
          const u32 swz  = (u32)lrow << 4;
          #pragma unroll
          for (int q = 0; q < 4; ++q) {
            const float x0 = acc[mi][ni][q * 4 + 0], x1 = acc[mi][ni][q * 4 + 1];
            const float x2 = acc[mi][ni][q * 4 + 2], x3 = acc[mi][ni][q * 4 + 3];
            u32x2 ph, pl;
            ph[0] = bfhi(x0) | (bfhi(x1) << 16);
            ph[1] = bfhi(x2) | (bfhi(x3) << 16);
            pl[0] = bflo(x0) | (bflo(x1) << 16);
            pl[1] = bflo(x2) | (bflo(x3) << 16);
            const u32 kg  = (u32)(w * 64 + mi * 32 + q * 8 + h * 4);
            const u32 off = rowb + ((kg * 2u) ^ swz);
            *(u32x2*)(vthi + off) = ph;
            *(u32x2*)(vtlo + off) = pl;
          }
        }
    }
    if (h == 0) {
      f32x2 p0, p1;
      p0[0] = pvz0; p0[1] = pvv0;
      p1[0] = pvz1; p1[1] = pvv1;
      *(f32x2*)(pbuf + (size_t)(w * 64 + lrow) * 2)      = p0;
      *(f32x2*)(pbuf + (size_t)(w * 64 + 32 + lrow) * 2) = p1;
    }
    __syncthreads();
    float svz0 = 0.f, svv0 = 0.f, svz1 = 0.f, svv1 = 0.f;
    #pragma unroll
    for (int w2 = 0; w2 < 8; ++w2) {
      f32x2 p0 = *(const f32x2*)(pbuf + (size_t)(w2 * 64 + lrow) * 2);
      f32x2 p1 = *(const f32x2*)(pbuf + (size_t)(w2 * 64 + 32 + lrow) * 2);
      svz0 += p0[0]; svv0 += p0[1];
      svz1 += p1[0]; svv1 += p1[1];
    }
    const float c0 = 2.0f * svz0 / svv0;
    const float c1 = 2.0f * svz1 / svv1;
    #pragma unroll
    for (int mi = 0; mi < 2; ++mi)
      #pragma unroll
      for (int r = 0; r < 16; ++r) {
        zf[mi][0][r] = fmaf(-c0, acc[mi][0][r], zf[mi][0][r]);
        zf[mi][1][r] = fmaf(-c1, acc[mi][1][r], zf[mi][1][r]);
      }
    #pragma unroll
    for (int mi = 0; mi < 2; ++mi) { acc[mi][0] = zero16(); acc[mi][1] = zero16(); }
  };

  // ---- layer 0: K=1024 via two staged chunks of hidden ----
  for (int c2 = 0; c2 < 2; ++c2) {
    stage_hidden(c2);
    __syncthreads();
    gemm(wf, 65536, c2 * 32);          // W0 frags: m-stride 64 ksteps * 1024 u16
    __syncthreads();
  }
  epilogue(b0v, true);

  // ---- layers 1..6 ----
  for (int t = 0; t < 6; ++t) {
    gemm(wf + W0_U16 + (size_t)t * WT_U16, 32768, 0);
    __syncthreads();
    epilogue(bsv + t * NCODE, t < 5);
  }

  // ---- store z ----
  #pragma unroll
  for (int mi = 0; mi < 2; ++mi)
    #pragma unroll
    for (int ni = 0; ni < 2; ++ni)
      #pragma unroll
      for (int q = 0; q < 4; ++q) {
        const int batch = brow + ni * 32 + lrow;
        const int n     = w * 64 + mi * 32 + q * 8 + h * 4;
        f32x4 v;
        #pragma unroll
        for (int c = 0; c < 4; ++c) v[c] = zf[mi][ni][q * 4 + c];
        *(f32x4*)(out + (size_t)batch * NCODE + n) = v;
      }
}

extern "C" void kernel_launch(void* const* d_in, const int* in_sizes, int n_in,
                              void* d_out, int out_size, void* d_ws, size_t ws_size,
                              hipStream_t stream)
{
  const float* hidden = (const float*)d_in[0];
  const float* zs     = (const float*)d_in[1];
  const float* W0     = (const float*)d_in[2];
  const float* b0v    = (const float*)d_in[3];
  const float* Ws     = (const float*)d_in[4];
  const float* bsv    = (const float*)d_in[5];
  float* out = (float*)d_out;
  u16*   wf  = (u16*)d_ws;   // needs 8 MiB

  hh_prep<<<1024, 256, 0, stream>>>(W0, Ws, wf);

  (void)hipFuncSetAttribute((const void*)hh_main, hipFuncAttributeMaxDynamicSharedMemorySize, 135168);
  hh_main<<<256, 512, 135168, stream>>>(hidden, zs, b0v, bsv, wf, out);
}

// Round 5
// 417.875 us; speedup vs baseline: 1.0520x; 1.0203x over previous
//
#include <hip/hip_runtime.h>

typedef unsigned int   u32;
typedef unsigned short u16;
typedef __attribute__((ext_vector_type(8)))  short  short8;
typedef __attribute__((ext_vector_type(16))) float  f32x16;
typedef __attribute__((ext_vector_type(4)))  float  f32x4;
typedef __attribute__((ext_vector_type(2)))  float  f32x2;
typedef __attribute__((ext_vector_type(4)))  u32    u32x4;
typedef __attribute__((ext_vector_type(2)))  u32    u32x2;

#define DEV static __device__ __forceinline__

// bf16 hi/lo split, truncation-based (residual <= 2^-16 relative)
DEV u32   bfhi(float f)   { return __float_as_uint(f) >> 16; }
DEV float bfhi_f(float f) { return __uint_as_float(__float_as_uint(f) & 0xFFFF0000u); }
DEV u32   bflo(float f)   { return __float_as_uint(f - bfhi_f(f)) >> 16; }

DEV f32x16 zero16() {
  f32x16 z;
  #pragma unroll
  for (int i = 0; i < 16; ++i) z[i] = 0.f;
  return z;
}

#define NBATCH 16384
#define NHID   1024
#define NCODE  512
#define TB     64
// ws layout in u16: W0 frags [0, 1048576), then 6x 524288 for Ws[t]
#define W0_U16 1048576
#define WT_U16 524288

// ---------------- prep: weights -> pre-swizzled bf16 hi/lo fragments ----------------
// Fragment block (m, ks, p): 1 KiB, lane l holds W[m*32 + (l&31)][ks*16 + (l>>5)*8 + j], j=0..7
__global__ __launch_bounds__(256)
void hh_prep(const float* __restrict__ W0, const float* __restrict__ Ws, u16* __restrict__ wf)
{
  const int tid  = blockIdx.x * 256 + threadIdx.x;
  const int task = tid >> 6;
  const int l    = tid & 63;
  const int lrow = l & 31;
  const int h    = l >> 5;
  const float* src;
  u16* dst;
  if (task < 1024) {                       // W0: m 0..15, ks 0..63
    const int m = task >> 6, ks = task & 63;
    src = W0 + (size_t)(m * 32 + lrow) * NHID + ks * 16 + h * 8;
    dst = wf + (size_t)task * 1024 + l * 8;
  } else {                                 // Ws: t 0..5, m 0..15, ks 0..31
    const int t2 = task - 1024;
    const int t = t2 >> 9, rr = t2 & 511;
    const int m = rr >> 5, ks = rr & 31;
    src = Ws + (size_t)t * (NCODE * NCODE) + (size_t)(m * 32 + lrow) * NCODE + ks * 16 + h * 8;
    dst = wf + W0_U16 + (size_t)t * WT_U16 + (size_t)rr * 1024 + l * 8;
  }
  f32x4 f0 = *(const f32x4*)(src);
  f32x4 f1 = *(const f32x4*)(src + 4);
  short8 hi, lo;
  #pragma unroll
  for (int j = 0; j < 4; ++j) {
    hi[j]     = (short)bfhi(f0[j]);  lo[j]     = (short)bflo(f0[j]);
    hi[j + 4] = (short)bfhi(f1[j]);  lo[j + 4] = (short)bflo(f1[j]);
  }
  *(short8*)(dst)       = hi;   // p=0 (hi)
  *(short8*)(dst + 512) = lo;   // p=1 (lo)
}

// ---------------- fused flow kernel ----------------
#define LDA(buf, kk) do { \
  const u16* _p = aPtr + (size_t)(kk) * 1024; \
  buf[0][0] = *(const short8*)(_p); \
  buf[0][1] = *(const short8*)(_p + 512); \
  buf[1][0] = *(const short8*)(_p + mStrideU16); \
  buf[1][1] = *(const short8*)(_p + mStrideU16 + 512); \
} while (0)

#define LDB(buf, kk) do { \
  const u32 _x = (u32)(kk) * 32u; \
  buf[0][0] = *(const short8*)(vthi + (bOff0 ^ _x)); \
  buf[0][1] = *(const short8*)(vtlo + (bOff0 ^ _x)); \
  buf[1][0] = *(const short8*)(vthi + (bOff1 ^ _x)); \
  buf[1][1] = *(const short8*)(vtlo + (bOff1 ^ _x)); \
} while (0)

#define MFMA_(a, b, c) __builtin_amdgcn_mfma_f32_32x32x16_bf16(a, b, c, 0, 0, 0)
// 3-pass hi/lo: hiA*hiB, loA*hiB, hiA*loB over the 2x2 tile grid
#define DO_MMA(A_, B_) do { \
  acc[0][0] = MFMA_(A_[0][0], B_[0][0], acc[0][0]); \
  acc[0][1] = MFMA_(A_[0][0], B_[1][0], acc[0][1]); \
  acc[1][0] = MFMA_(A_[1][0], B_[0][0], acc[1][0]); \
  acc[1][1] = MFMA_(A_[1][0], B_[1][0], acc[1][1]); \
  acc[0][0] = MFMA_(A_[0][1], B_[0][0], acc[0][0]); \
  acc[0][1] = MFMA_(A_[0][1], B_[1][0], acc[0][1]); \
  acc[1][0] = MFMA_(A_[1][1], B_[0][0], acc[1][0]); \
  acc[1][1] = MFMA_(A_[1][1], B_[1][0], acc[1][1]); \
  acc[0][0] = MFMA_(A_[0][0], B_[0][1], acc[0][0]); \
  acc[0][1] = MFMA_(A_[0][0], B_[1][1], acc[0][1]); \
  acc[1][0] = MFMA_(A_[1][0], B_[0][1], acc[1][0]); \
  acc[1][1] = MFMA_(A_[1][0], B_[1][1], acc[1][1]); \
} while (0)

__global__ __launch_bounds__(512)
__attribute__((amdgpu_waves_per_eu(2, 2)))
void hh_main(const float* __restrict__ hidden, const float* __restrict__ zs,
             const float* __restrict__ b0v, const float* __restrict__ bsv,
             const u16* __restrict__ wf, float* __restrict__ out)
{
  extern __shared__ char smem[];
  char*  vthi = smem;                       // 64 KiB: v^T hi, [64 batch][512 k] bf16, XOR-swizzled
  char*  vtlo = smem + 65536;               // 64 KiB: v^T lo
  float* pbuf = (float*)(smem + 131072);    // [8 waves][64 batch][2] partial {vz, vv}

  const int tid  = threadIdx.x;
  const int w    = tid >> 6;     // wave id: owns out-rows [w*64, w*64+64)
  const int l    = tid & 63;
  const int lrow = l & 31;
  const int h    = l >> 5;
  const int brow = blockIdx.x * TB;

  f32x16 acc[2][2];   // [mi out-tile][ni batch-tile]; C layout: col=lane&31=batch, row=(r&3)+8*(r>>2)+4*h
  f32x16 zf[2][2];    // z held in identical layout

  // ---- z init from zs ----
  #pragma unroll
  for (int mi = 0; mi < 2; ++mi)
    #pragma unroll
    for (int ni = 0; ni < 2; ++ni)
      #pragma unroll
      for (int q = 0; q < 4; ++q) {
        const int batch = brow + ni * 32 + lrow;
        const int n     = w * 64 + mi * 32 + q * 8 + h * 4;
        f32x4 v = *(const f32x4*)(zs + (size_t)batch * NCODE + n);
        #pragma unroll
        for (int c = 0; c < 4; ++c) zf[mi][ni][q * 4 + c] = v[c];
      }
  #pragma unroll
  for (int mi = 0; mi < 2; ++mi) { acc[mi][0] = zero16(); acc[mi][1] = zero16(); }

  // ---- stage hidden chunk (512 k) into VT hi/lo, cooperatively ----
  auto stage_hidden = [&](int c2) {
    const int bloc = tid >> 3;          // 0..63 batch row
    const int kc   = tid & 7;           // 0..7  k-chunk of 64
    const float* src = hidden + (size_t)(brow + bloc) * NHID + c2 * 512 + kc * 64;
    const u32 rowb = (u32)bloc * 1024u;
    const u32 swz  = ((u32)bloc & 31u) << 4;
    #pragma unroll
    for (int i = 0; i < 8; ++i) {
      f32x4 f0 = *(const f32x4*)(src + i * 8);
      f32x4 f1 = *(const f32x4*)(src + i * 8 + 4);
      u32x4 sh, sl;
      sh[0] = bfhi(f0[0]) | (bfhi(f0[1]) << 16);
      sh[1] = bfhi(f0[2]) | (bfhi(f0[3]) << 16);
      sh[2] = bfhi(f1[0]) | (bfhi(f1[1]) << 16);
      sh[3] = bfhi(f1[2]) | (bfhi(f1[3]) << 16);
      sl[0] = bflo(f0[0]) | (bflo(f0[1]) << 16);
      sl[1] = bflo(f0[2]) | (bflo(f0[3]) << 16);
      sl[2] = bflo(f1[0]) | (bflo(f1[1]) << 16);
      sl[3] = bflo(f1[2]) | (bflo(f1[3]) << 16);
      const u32 kloc = (u32)(kc * 64 + i * 8);
      const u32 off  = rowb + ((kloc * 2u) ^ swz);
      *(u32x4*)(vthi + off) = sh;
      *(u32x4*)(vtlo + off) = sl;
    }
  };

  // ---- one 512-K GEMM pass: acc += W_frag * VT ----
  auto gemm = [&](const u16* aBase, int mStrideU16, int ksOff) {
    const u16* aPtr = aBase + (size_t)(w * 2) * mStrideU16 + (size_t)ksOff * 1024 + (size_t)l * 8;
    const u32 bOff0 = (u32)lrow * 1024u + (((u32)h * 16u) ^ ((u32)lrow << 4));
    const u32 bOff1 = bOff0 + 32768u;   // ni=1 -> +32 rows
    short8 A0[2][2], A1[2][2], B0[2][2], B1[2][2];
    LDA(A0, 0); LDB(B0, 0);
    for (int kp = 0; kp < 15; ++kp) {
      LDA(A1, 2 * kp + 1); LDB(B1, 2 * kp + 1);
      DO_MMA(A0, B0);
      LDA(A0, 2 * kp + 2); LDB(B0, 2 * kp + 2);
      DO_MMA(A1, B1);
    }
    LDA(A1, 31); LDB(B1, 31);
    DO_MMA(A0, B0);
    DO_MMA(A1, B1);
  };

  // ---- epilogue: bias, HH partials, write v^T hi/lo, barrier, z update, clear acc ----
  auto epilogue = [&](const float* bias, bool writeVT) {
    #pragma unroll
    for (int mi = 0; mi < 2; ++mi)
      #pragma unroll
      for (int q = 0; q < 4; ++q) {
        f32x4 bb = *(const f32x4*)(bias + w * 64 + mi * 32 + q * 8 + h * 4);
        #pragma unroll
        for (int c = 0; c < 4; ++c) {
          acc[mi][0][q * 4 + c] += bb[c];
          acc[mi][1][q * 4 + c] += bb[c];
        }
      }
    float pvz0 = 0.f, pvv0 = 0.f, pvz1 = 0.f, pvv1 = 0.f;
    #pragma unroll
    for (int mi = 0; mi < 2; ++mi)
      #pragma unroll
      for (int r = 0; r < 16; ++r) {
        pvz0 += acc[mi][0][r] * zf[mi][0][r];
        pvv0 += acc[mi][0][r] * acc[mi][0][r];
        pvz1 += acc[mi][1][r] * zf[mi][1][r];
        pvv1 += acc[mi][1][r] * acc[mi][1][r];
      }
    pvz0 += __shfl_xor(pvz0, 32); pvv0 += __shfl_xor(pvv0, 32);
    pvz1 += __shfl_xor(pvz1, 32); pvv1 += __shfl_xor(pvv1, 32);

    if (writeVT) {
      #pragma unroll
      for (int mi = 0; mi < 2; ++mi)
        #pragma unroll
        for (int ni = 0; ni < 2; ++ni) {
          const u32 rowb = (u32)(ni * 32 + lrow) * 1024u;
          const u32 swz  = (u32)lrow << 4;
          #pragma unroll
          for (int q = 0; q < 4; ++q) {
            const float x0 = acc[mi][ni][q * 4 + 0], x1 = acc[mi][ni][q * 4 + 1];
            const float x2 = acc[mi][ni][q * 4 + 2], x3 = acc[mi][ni][q * 4 + 3];
            u32x2 ph, pl;
            ph[0] = bfhi(x0) | (bfhi(x1) << 16);
            ph[1] = bfhi(x2) | (bfhi(x3) << 16);
            pl[0] = bflo(x0) | (bflo(x1) << 16);
            pl[1] = bflo(x2) | (bflo(x3) << 16);
            const u32 kg  = (u32)(w * 64 + mi * 32 + q * 8 + h * 4);
            const u32 off = rowb + ((kg * 2u) ^ swz);
            *(u32x2*)(vthi + off) = ph;
            *(u32x2*)(vtlo + off) = pl;
          }
        }
    }
    if (h == 0) {
      f32x2 p0, p1;
      p0[0] = pvz0; p0[1] = pvv0;
      p1[0] = pvz1; p1[1] = pvv1;
      *(f32x2*)(pbuf + (size_t)(w * 64 + lrow) * 2)      = p0;
      *(f32x2*)(pbuf + (size_t)(w * 64 + 32 + lrow) * 2) = p1;
    }
    __syncthreads();
    float svz0 = 0.f, svv0 = 0.f, svz1 = 0.f, svv1 = 0.f;
    #pragma unroll
    for (int w2 = 0; w2 < 8; ++w2) {
      f32x2 p0 = *(const f32x2*)(pbuf + (size_t)(w2 * 64 + lrow) * 2);
      f32x2 p1 = *(const f32x2*)(pbuf + (size_t)(w2 * 64 + 32 + lrow) * 2);
      svz0 += p0[0]; svv0 += p0[1];
      svz1 += p1[0]; svv1 += p1[1];
    }
    const float c0 = 2.0f * svz0 / svv0;
    const float c1 = 2.0f * svz1 / svv1;
    #pragma unroll
    for (int mi = 0; mi < 2; ++mi)
      #pragma unroll
      for (int r = 0; r < 16; ++r) {
        zf[mi][0][r] = fmaf(-c0, acc[mi][0][r], zf[mi][0][r]);
        zf[mi][1][r] = fmaf(-c1, acc[mi][1][r], zf[mi][1][r]);
      }
    #pragma unroll
    for (int mi = 0; mi < 2; ++mi) { acc[mi][0] = zero16(); acc[mi][1] = zero16(); }
  };

  // ---- layer 0: K=1024 via two staged chunks of hidden ----
  for (int c2 = 0; c2 < 2; ++c2) {
    stage_hidden(c2);
    __syncthreads();
    gemm(wf, 65536, c2 * 32);          // W0 frags: m-stride 64 ksteps * 1024 u16
    __syncthreads();
  }
  epilogue(b0v, true);

  // ---- layers 1..6 ----
  for (int t = 0; t < 6; ++t) {
    gemm(wf + W0_U16 + (size_t)t * WT_U16, 32768, 0);
    __syncthreads();
    epilogue(bsv + t * NCODE, t < 5);
  }

  // ---- store z ----
  #pragma unroll
  for (int mi = 0; mi < 2; ++mi)
    #pragma unroll
    for (int ni = 0; ni < 2; ++ni)
      #pragma unroll
      for (int q = 0; q < 4; ++q) {
        const int batch = brow + ni * 32 + lrow;
        const int n     = w * 64 + mi * 32 + q * 8 + h * 4;
        f32x4 v;
        #pragma unroll
        for (int c = 0; c < 4; ++c) v[c] = zf[mi][ni][q * 4 + c];
        *(f32x4*)(out + (size_t)batch * NCODE + n) = v;
      }
}

extern "C" void kernel_launch(void* const* d_in, const int* in_sizes, int n_in,
                              void* d_out, int out_size, void* d_ws, size_t ws_size,
                              hipStream_t stream)
{
  const float* hidden = (const float*)d_in[0];
  const float* zs     = (const float*)d_in[1];
  const float* W0     = (const float*)d_in[2];
  const float* b0v    = (const float*)d_in[3];
  const float* Ws     = (const float*)d_in[4];
  const float* bsv    = (const float*)d_in[5];
  float* out = (float*)d_out;
  u16*   wf  = (u16*)d_ws;   // needs 8 MiB

  hh_prep<<<1024, 256, 0, stream>>>(W0, Ws, wf);

  (void)hipFuncSetAttribute((const void*)hh_main, hipFuncAttributeMaxDynamicSharedMemorySize, 135168);
  hh_main<<<256, 512, 135168, stream>>>(hidden, zs, b0v, bsv, wf, out);
}

// Round 7
// 336.954 us; speedup vs baseline: 1.3046x; 1.2402x over previous
//
#include <hip/hip_runtime.h>

typedef unsigned int   u32;
typedef unsigned short u16;
typedef __attribute__((ext_vector_type(8)))  short  short8;
typedef __attribute__((ext_vector_type(16))) float  f32x16;
typedef __attribute__((ext_vector_type(4)))  float  f32x4;
typedef __attribute__((ext_vector_type(2)))  float  f32x2;
typedef __attribute__((ext_vector_type(4)))  u32    u32x4;
typedef __attribute__((ext_vector_type(2)))  u32    u32x2;

#define DEV static __device__ __forceinline__

// bf16 hi/lo split, truncation-based (residual <= 2^-16 relative)
DEV u32   bfhi(float f)   { return __float_as_uint(f) >> 16; }
DEV float bfhi_f(float f) { return __uint_as_float(__float_as_uint(f) & 0xFFFF0000u); }
DEV u32   bflo(float f)   { return __float_as_uint(f - bfhi_f(f)) >> 16; }

DEV f32x16 zero16() {
  f32x16 z;
  #pragma unroll
  for (int i = 0; i < 16; ++i) z[i] = 0.f;
  return z;
}

#define NBATCH 16384
#define NHID   1024
#define NCODE  512
#define TB     64
// ws layout in u16: W0 frags [0, 1048576), then 6x 524288 for Ws[t]
#define W0_U16 1048576
#define WT_U16 524288

// ---------------- prep: weights -> pre-swizzled bf16 hi/lo fragments ----------------
// Fragment block (m, ks, p): 1 KiB, lane l holds W[m*32 + (l&31)][ks*16 + (l>>5)*8 + j], j=0..7
__global__ __launch_bounds__(256)
void hh_prep(const float* __restrict__ W0, const float* __restrict__ Ws, u16* __restrict__ wf)
{
  const int tid  = blockIdx.x * 256 + threadIdx.x;
  const int task = tid >> 6;
  const int l    = tid & 63;
  const int lrow = l & 31;
  const int h    = l >> 5;
  const float* src;
  u16* dst;
  if (task < 1024) {                       // W0: m 0..15, ks 0..63
    const int m = task >> 6, ks = task & 63;
    src = W0 + (size_t)(m * 32 + lrow) * NHID + ks * 16 + h * 8;
    dst = wf + (size_t)task * 1024 + l * 8;
  } else {                                 // Ws: t 0..5, m 0..15, ks 0..31
    const int t2 = task - 1024;
    const int t = t2 >> 9, rr = t2 & 511;
    const int m = rr >> 5, ks = rr & 31;
    src = Ws + (size_t)t * (NCODE * NCODE) + (size_t)(m * 32 + lrow) * NCODE + ks * 16 + h * 8;
    dst = wf + W0_U16 + (size_t)t * WT_U16 + (size_t)rr * 1024 + l * 8;
  }
  f32x4 f0 = *(const f32x4*)(src);
  f32x4 f1 = *(const f32x4*)(src + 4);
  short8 hi, lo;
  #pragma unroll
  for (int j = 0; j < 4; ++j) {
    hi[j]     = (short)bfhi(f0[j]);  lo[j]     = (short)bflo(f0[j]);
    hi[j + 4] = (short)bfhi(f1[j]);  lo[j + 4] = (short)bflo(f1[j]);
  }
  *(short8*)(dst)       = hi;   // p=0 (hi)
  *(short8*)(dst + 512) = lo;   // p=1 (lo)
}

// ---------------- fused flow kernel ----------------
#define LDA(buf, kk) do { \
  const u16* _p = aPtr + (size_t)(kk) * 1024; \
  buf[0][0] = *(const short8*)(_p); \
  buf[0][1] = *(const short8*)(_p + 512); \
  buf[1][0] = *(const short8*)(_p + mStrideU16); \
  buf[1][1] = *(const short8*)(_p + mStrideU16 + 512); \
} while (0)

#define LDB(buf, kk) do { \
  const u32 _x = (u32)(kk) * 32u; \
  buf[0][0] = *(const short8*)(vthi + (bOff0 ^ _x)); \
  buf[0][1] = *(const short8*)(vtlo + (bOff0 ^ _x)); \
  buf[1][0] = *(const short8*)(vthi + (bOff1 ^ _x)); \
  buf[1][1] = *(const short8*)(vtlo + (bOff1 ^ _x)); \
} while (0)

#define MFMA_(a, b, c) __builtin_amdgcn_mfma_f32_32x32x16_bf16(a, b, c, 0, 0, 0)
// 3-pass hi/lo: hiA*hiB, loA*hiB, hiA*loB over the 2x2 tile grid
#define DO_MMA(A_, B_) do { \
  acc[0][0] = MFMA_(A_[0][0], B_[0][0], acc[0][0]); \
  acc[0][1] = MFMA_(A_[0][0], B_[1][0], acc[0][1]); \
  acc[1][0] = MFMA_(A_[1][0], B_[0][0], acc[1][0]); \
  acc[1][1] = MFMA_(A_[1][0], B_[1][0], acc[1][1]); \
  acc[0][0] = MFMA_(A_[0][1], B_[0][0], acc[0][0]); \
  acc[0][1] = MFMA_(A_[0][1], B_[1][0], acc[0][1]); \
  acc[1][0] = MFMA_(A_[1][1], B_[0][0], acc[1][0]); \
  acc[1][1] = MFMA_(A_[1][1], B_[1][0], acc[1][1]); \
  acc[0][0] = MFMA_(A_[0][0], B_[0][1], acc[0][0]); \
  acc[0][1] = MFMA_(A_[0][0], B_[1][1], acc[0][1]); \
  acc[1][0] = MFMA_(A_[1][0], B_[0][1], acc[1][0]); \
  acc[1][1] = MFMA_(A_[1][0], B_[1][1], acc[1][1]); \
} while (0)

__global__ __launch_bounds__(512)
__attribute__((amdgpu_waves_per_eu(2, 2)))
void hh_main(const float* __restrict__ hidden, const float* __restrict__ zs,
             const float* __restrict__ b0v, const float* __restrict__ bsv,
             const u16* __restrict__ wf, float* __restrict__ out)
{
  extern __shared__ char smem[];
  char*  vthi = smem;                       // 64 KiB: v^T hi, [64 batch][512 k] bf16, XOR-swizzled
  char*  vtlo = smem + 65536;               // 64 KiB: v^T lo
  float* pbuf = (float*)(smem + 131072);    // [8 waves][64 batch][2] partial {vz, vv}

  const int tid  = threadIdx.x;
  const int w    = tid >> 6;     // wave id: owns out-rows [w*64, w*64+64)
  const int l    = tid & 63;
  const int lrow = l & 31;
  const int h    = l >> 5;
  const int brow = blockIdx.x * TB;

  f32x16 acc[2][2];   // [mi out-tile][ni batch-tile]; C layout: col=lane&31=batch, row=(r&3)+8*(r>>2)+4*h
  f32x16 zf[2][2];    // z held in identical layout

  // ---- z init from zs ----
  #pragma unroll
  for (int mi = 0; mi < 2; ++mi)
    #pragma unroll
    for (int ni = 0; ni < 2; ++ni)
      #pragma unroll
      for (int q = 0; q < 4; ++q) {
        const int batch = brow + ni * 32 + lrow;
        const int n     = w * 64 + mi * 32 + q * 8 + h * 4;
        f32x4 v = *(const f32x4*)(zs + (size_t)batch * NCODE + n);
        #pragma unroll
        for (int c = 0; c < 4; ++c) zf[mi][ni][q * 4 + c] = v[c];
      }
  #pragma unroll
  for (int mi = 0; mi < 2; ++mi) { acc[mi][0] = zero16(); acc[mi][1] = zero16(); }

  // ---- stage hidden chunk (512 k) into VT hi/lo, cooperatively ----
  auto stage_hidden = [&](int c2) {
    const int bloc = tid >> 3;          // 0..63 batch row
    const int kc   = tid & 7;           // 0..7  k-chunk of 64
    const float* src = hidden + (size_t)(brow + bloc) * NHID + c2 * 512 + kc * 64;
    const u32 rowb = (u32)bloc * 1024u;
    const u32 swz  = ((u32)bloc & 31u) << 4;
    #pragma unroll
    for (int i = 0; i < 8; ++i) {
      f32x4 f0 = *(const f32x4*)(src + i * 8);
      f32x4 f1 = *(const f32x4*)(src + i * 8 + 4);
      u32x4 sh, sl;
      sh[0] = bfhi(f0[0]) | (bfhi(f0[1]) << 16);
      sh[1] = bfhi(f0[2]) | (bfhi(f0[3]) << 16);
      sh[2] = bfhi(f1[0]) | (bfhi(f1[1]) << 16);
      sh[3] = bfhi(f1[2]) | (bfhi(f1[3]) << 16);
      sl[0] = bflo(f0[0]) | (bflo(f0[1]) << 16);
      sl[1] = bflo(f0[2]) | (bflo(f0[3]) << 16);
      sl[2] = bflo(f1[0]) | (bflo(f1[1]) << 16);
      sl[3] = bflo(f1[2]) | (bflo(f1[3]) << 16);
      const u32 kloc = (u32)(kc * 64 + i * 8);
      const u32 off  = rowb + ((kloc * 2u) ^ swz);
      *(u32x4*)(vthi + off) = sh;
      *(u32x4*)(vtlo + off) = sl;
    }
  };

  // ---- one 512-K GEMM pass: acc += W_frag * VT (single-buffered frags, no spill) ----
  auto gemm = [&](const u16* aBase, int mStrideU16, int ksOff) {
    const u16* aPtr = aBase + (size_t)(w * 2) * mStrideU16 + (size_t)ksOff * 1024 + (size_t)l * 8;
    const u32 bOff0 = (u32)lrow * 1024u + (((u32)h * 16u) ^ ((u32)lrow << 4));
    const u32 bOff1 = bOff0 + 32768u;   // ni=1 -> +32 rows
    short8 A0[2][2], B0[2][2];
    #pragma unroll 1
    for (int kk = 0; kk < 32; ++kk) {
      LDA(A0, kk);
      LDB(B0, kk);
      DO_MMA(A0, B0);
    }
  };

  // ---- epilogue: bias, HH partials, write v^T hi/lo, barrier, z update, clear acc ----
  auto epilogue = [&](const float* bias, bool writeVT) {
    #pragma unroll
    for (int mi = 0; mi < 2; ++mi)
      #pragma unroll
      for (int q = 0; q < 4; ++q) {
        f32x4 bb = *(const f32x4*)(bias + w * 64 + mi * 32 + q * 8 + h * 4);
        #pragma unroll
        for (int c = 0; c < 4; ++c) {
          acc[mi][0][q * 4 + c] += bb[c];
          acc[mi][1][q * 4 + c] += bb[c];
        }
      }
    float pvz0 = 0.f, pvv0 = 0.f, pvz1 = 0.f, pvv1 = 0.f;
    #pragma unroll
    for (int mi = 0; mi < 2; ++mi)
      #pragma unroll
      for (int r = 0; r < 16; ++r) {
        pvz0 += acc[mi][0][r] * zf[mi][0][r];
        pvv0 += acc[mi][0][r] * acc[mi][0][r];
        pvz1 += acc[mi][1][r] * zf[mi][1][r];
        pvv1 += acc[mi][1][r] * acc[mi][1][r];
      }
    pvz0 += __shfl_xor(pvz0, 32); pvv0 += __shfl_xor(pvv0, 32);
    pvz1 += __shfl_xor(pvz1, 32); pvv1 += __shfl_xor(pvv1, 32);

    if (writeVT) {
      #pragma unroll
      for (int mi = 0; mi < 2; ++mi)
        #pragma unroll
        for (int ni = 0; ni < 2; ++ni) {
          const u32 rowb = (u32)(ni * 32 + lrow) * 1024u;
          const u32 swz  = (u32)lrow << 4;
          #pragma unroll
          for (int q = 0; q < 4; ++q) {
            const float x0 = acc[mi][ni][q * 4 + 0], x1 = acc[mi][ni][q * 4 + 1];
            const float x2 = acc[mi][ni][q * 4 + 2], x3 = acc[mi][ni][q * 4 + 3];
            u32x2 ph, pl;
            ph[0] = bfhi(x0) | (bfhi(x1) << 16);
            ph[1] = bfhi(x2) | (bfhi(x3) << 16);
            pl[0] = bflo(x0) | (bflo(x1) << 16);
            pl[1] = bflo(x2) | (bflo(x3) << 16);
            const u32 kg  = (u32)(w * 64 + mi * 32 + q * 8 + h * 4);
            const u32 off = rowb + ((kg * 2u) ^ swz);
            *(u32x2*)(vthi + off) = ph;
            *(u32x2*)(vtlo + off) = pl;
          }
        }
    }
    if (h == 0) {
      f32x2 p0, p1;
      p0[0] = pvz0; p0[1] = pvv0;
      p1[0] = pvz1; p1[1] = pvv1;
      *(f32x2*)(pbuf + (size_t)(w * 64 + lrow) * 2)      = p0;
      *(f32x2*)(pbuf + (size_t)(w * 64 + 32 + lrow) * 2) = p1;
    }
    __syncthreads();
    float svz0 = 0.f, svv0 = 0.f, svz1 = 0.f, svv1 = 0.f;
    #pragma unroll
    for (int w2 = 0; w2 < 8; ++w2) {
      f32x2 p0 = *(const f32x2*)(pbuf + (size_t)(w2 * 64 + lrow) * 2);
      f32x2 p1 = *(const f32x2*)(pbuf + (size_t)(w2 * 64 + 32 + lrow) * 2);
      svz0 += p0[0]; svv0 += p0[1];
      svz1 += p1[0]; svv1 += p1[1];
    }
    const float c0 = 2.0f * svz0 / svv0;
    const float c1 = 2.0f * svz1 / svv1;
    #pragma unroll
    for (int mi = 0; mi < 2; ++mi)
      #pragma unroll
      for (int r = 0; r < 16; ++r) {
        zf[mi][0][r] = fmaf(-c0, acc[mi][0][r], zf[mi][0][r]);
        zf[mi][1][r] = fmaf(-c1, acc[mi][1][r], zf[mi][1][r]);
      }
    #pragma unroll
    for (int mi = 0; mi < 2; ++mi) { acc[mi][0] = zero16(); acc[mi][1] = zero16(); }
  };

  // ---- layer 0: K=1024 via two staged chunks of hidden ----
  for (int c2 = 0; c2 < 2; ++c2) {
    stage_hidden(c2);
    __syncthreads();
    gemm(wf, 65536, c2 * 32);          // W0 frags: m-stride 64 ksteps * 1024 u16
    __syncthreads();
  }
  epilogue(b0v, true);

  // ---- layers 1..6 ----
  for (int t = 0; t < 6; ++t) {
    gemm(wf + W0_U16 + (size_t)t * WT_U16, 32768, 0);
    __syncthreads();
    epilogue(bsv + t * NCODE, t < 5);
  }

  // ---- store z ----
  #pragma unroll
  for (int mi = 0; mi < 2; ++mi)
    #pragma unroll
    for (int ni = 0; ni < 2; ++ni)
      #pragma unroll
      for (int q = 0; q < 4; ++q) {
        const int batch = brow + ni * 32 + lrow;
        const int n     = w * 64 + mi * 32 + q * 8 + h * 4;
        f32x4 v;
        #pragma unroll
        for (int c = 0; c < 4; ++c) v[c] = zf[mi][ni][q * 4 + c];
        *(f32x4*)(out + (size_t)batch * NCODE + n) = v;
      }
}

extern "C" void kernel_launch(void* const* d_in, const int* in_sizes, int n_in,
                              void* d_out, int out_size, void* d_ws, size_t ws_size,
                              hipStream_t stream)
{
  const float* hidden = (const float*)d_in[0];
  const float* zs     = (const float*)d_in[1];
  const float* W0     = (const float*)d_in[2];
  const float* b0v    = (const float*)d_in[3];
  const float* Ws     = (const float*)d_in[4];
  const float* bsv    = (const float*)d_in[5];
  float* out = (float*)d_out;
  u16*   wf  = (u16*)d_ws;   // needs 8 MiB

  hh_prep<<<1024, 256, 0, stream>>>(W0, Ws, wf);

  (void)hipFuncSetAttribute((const void*)hh_main, hipFuncAttributeMaxDynamicSharedMemorySize, 135168);
  hh_main<<<256, 512, 135168, stream>>>(hidden, zs, b0v, bsv, wf, out);
}